// Round 9
// baseline (203.056 us; speedup 1.0000x reference)
//
#include <hip/hip_runtime.h>

// WhiteSoftmax: B=8192, C=64, O=128, 256 states, 256 vals.
//   K_pack:  add_table int32 -> u8 (8 MB ws).
//   K_fused: 512 thr x 4 chains = 2048 chains/block, 256 blocks (1/CU).
//     phase 1: coalesced x -> byte-pack -> LDS transpose -> pxA..pxD regs
//              (sets: chains [0,512)=A [512,1024)=B [1024,1536)=C [1536,2048)=D).
//     phase 2: 128-step walk; 64 KB u8 table slice double-buffered in LDS via
//              global_load_lds(16B, 8/thread) + counted vmcnt(8) + s_barrier;
//              4 independent ds_read_u8 gathers/thread/step; 8-wave barriers.
//     phase 3: restage softmax_table as bf16 into dead slice LDS (128 KB);
//              16 chunks x 128 chains: owner threads deposit px+s, all waves
//              gather from LDS + coalesced nontemporal float4 store.

constexpr int O_DIM = 128;
constexpr long long NCHAINS = 8192LL * 64;        // 524288
constexpr int TAB_ENTRIES = 128 * 256 * 256;      // 8 MB u8

typedef int   vi4 __attribute__((ext_vector_type(4)));
typedef float vf4 __attribute__((ext_vector_type(4)));

__global__ __launch_bounds__(256)
void pack_kernel(const int* __restrict__ t32, unsigned char* __restrict__ t8) {
    const int i = (blockIdx.x * 256 + threadIdx.x) * 4;
    vi4 v = *reinterpret_cast<const vi4*>(t32 + i);
    unsigned b = ((unsigned)v.x & 0xffu) | (((unsigned)v.y & 0xffu) << 8) |
                 (((unsigned)v.z & 0xffu) << 16) | (((unsigned)v.w & 0xffu) << 24);
    *reinterpret_cast<unsigned*>(t8 + i) = b;
}

__device__ __forceinline__ unsigned f2bf(float f) {
    unsigned b = __float_as_uint(f);
    return (b + 0x7fffu + ((b >> 16) & 1u)) >> 16;
}
__device__ __forceinline__ float bf2f(unsigned short h) {
    return __uint_as_float(((unsigned)h) << 16);
}

constexpr int WBLK = 512;                         // threads per block
constexpr int WCH  = 2048;                        // chains per block (4/thread)

__global__ __launch_bounds__(WBLK, 2)
void fused_ws(const int* __restrict__ x, const unsigned char* __restrict__ t8,
              const float* __restrict__ st, float* __restrict__ out) {
    __shared__ unsigned char slice[2][65536];     // walk slices / p1 scratch / st bf16
    __shared__ unsigned px_out[128 * 32];         // 16 KB output px scratch
    __shared__ int s_l[128];
    unsigned* pxw = reinterpret_cast<unsigned*>(&slice[0][0]);

    const int t = threadIdx.x;
    const size_t chain0 = (size_t)blockIdx.x * WCH;

    unsigned pxA[32], pxB[32], pxC[32], pxD[32];

    // ---- phase 1: two 1024-chain windows: coalesced x load -> pack ->
    //      swizzled LDS transpose -> 2 chain-sets per window into regs ----
    auto window = [&](int w, unsigned (&d0)[32], unsigned (&d1)[32]) {
        const vi4* xv = reinterpret_cast<const vi4*>(x + (chain0 + (size_t)w * 1024) * O_DIM);
#pragma unroll 4
        for (int k = 0; k < 64; ++k) {
            const int idx = k * WBLK + t;          // 32768 int4 in window tile
            vi4 v = __builtin_nontemporal_load(&xv[idx]);
            unsigned p = (unsigned)v.x | ((unsigned)v.y << 8) |
                         ((unsigned)v.z << 16) | ((unsigned)v.w << 24);
            const int cl = idx >> 5;               // chain-local 0..1023
            const int d  = idx & 31;
            pxw[cl * 32 + (d ^ (cl & 31))] = p;
        }
        __syncthreads();
#pragma unroll
        for (int k = 0; k < 32; ++k) {
            d0[k] = pxw[t * 32 + (k ^ (t & 31))];
            d1[k] = pxw[(512 + t) * 32 + (k ^ (t & 31))];
        }
        __syncthreads();                           // pxw reads done before reuse
    };
    window(0, pxA, pxB);
    window(1, pxC, pxD);

    // ---- phase 2: 128-step walk, LDS slice double-buffer ----
    auto stage = [&](int j, int b) {
        const unsigned char* gsrc = t8 + ((size_t)j << 16);
#pragma unroll
        for (int r = 0; r < 8; ++r) {
            __builtin_amdgcn_global_load_lds(
                (const __attribute__((address_space(1))) void*)(gsrc + r * 8192 + t * 16),
                (__attribute__((address_space(3))) void*)(&slice[b][r * 8192 + t * 16]),
                16, 0, 0);
        }
    };

    stage(0, 0);
    asm volatile("s_waitcnt vmcnt(0)" ::: "memory");
    __builtin_amdgcn_s_barrier();

    int s0 = 0, s1 = 0, s2 = 0, s3 = 0;
#pragma unroll
    for (int j = 0; j < 127; ++j) {
        stage(j + 1, (j + 1) & 1);                     // issue next slice (8 loads)
        asm volatile("s_waitcnt vmcnt(8)" ::: "memory"); // slice j landed (my share)
        __builtin_amdgcn_s_barrier();                   // all waves' shares landed
        const int buf = j & 1;
        const int sh = (j & 3) * 8;
        const unsigned b0 = (pxA[j >> 2] >> sh) & 0xffu;
        const unsigned b1 = (pxB[j >> 2] >> sh) & 0xffu;
        const unsigned b2 = (pxC[j >> 2] >> sh) & 0xffu;
        const unsigned b3 = (pxD[j >> 2] >> sh) & 0xffu;
        s0 = slice[buf][((unsigned)s0 << 8) | b0];
        s1 = slice[buf][((unsigned)s1 << 8) | b1];
        s2 = slice[buf][((unsigned)s2 << 8) | b2];
        s3 = slice[buf][((unsigned)s3 << 8) | b3];
        asm volatile("s_waitcnt lgkmcnt(0)" ::: "memory"); // my gathers done
        __builtin_amdgcn_s_barrier();                   // all gathers done before overwrite
    }
    asm volatile("s_waitcnt vmcnt(0)" ::: "memory");
    __builtin_amdgcn_s_barrier();
    {
        s0 = slice[1][((unsigned)s0 << 8) | (pxA[31] >> 24)];
        s1 = slice[1][((unsigned)s1 << 8) | (pxB[31] >> 24)];
        s2 = slice[1][((unsigned)s2 << 8) | (pxC[31] >> 24)];
        s3 = slice[1][((unsigned)s3 << 8) | (pxD[31] >> 24)];
    }
    __syncthreads();                                    // final gathers done, slices dead

    // ---- phase 3: st -> bf16 in slice LDS, chunked coalesced output ----
    unsigned* stl32 = reinterpret_cast<unsigned*>(&slice[0][0]);
    unsigned short* st_l = reinterpret_cast<unsigned short*>(&slice[0][0]);
    const vf4* stv = reinterpret_cast<const vf4*>(st);
#pragma unroll 4
    for (int k = 0; k < 32; ++k) {
        const int idx = k * WBLK + t;              // 16384 vf4 = 64K floats
        vf4 v = stv[idx];
        stl32[idx * 2]     = f2bf(v.x) | (f2bf(v.y) << 16);
        stl32[idx * 2 + 1] = f2bf(v.z) | (f2bf(v.w) << 16);
    }
    __syncthreads();

#pragma unroll
    for (int cc = 0; cc < 16; ++cc) {              // 16 chunks x 128 chains
        const int set = cc >> 2;                   // static under unroll
        const unsigned (&pp)[32] = set == 0 ? pxA : set == 1 ? pxB :
                                   set == 2 ? pxC : pxD;
        const int sv = set == 0 ? s0 : set == 1 ? s1 : set == 2 ? s2 : s3;
        if ((t >> 7) == (cc & 3)) {                // 128 owner threads deposit
            const int lc = t & 127;
            s_l[lc] = sv;
#pragma unroll
            for (int k = 0; k < 32; ++k)
                px_out[lc * 32 + (k ^ (lc & 31))] = pp[k];
        }
        __syncthreads();
        vf4* ov = reinterpret_cast<vf4*>(out + (chain0 + (size_t)cc * 128) * O_DIM);
#pragma unroll
        for (int k = 0; k < 8; ++k) {
            const int idx = k * WBLK + t;          // 4096 vf4 per chunk
            const int cl = idx >> 5, q = idx & 31;
            unsigned p = px_out[cl * 32 + (q ^ (cl & 31))];
            const int row = s_l[cl] << 8;
            vf4 r;
            r.x = bf2f((unsigned short)st_l[row + (p & 0xffu)]);
            r.y = bf2f((unsigned short)st_l[row + ((p >> 8) & 0xffu)]);
            r.z = bf2f((unsigned short)st_l[row + ((p >> 16) & 0xffu)]);
            r.w = bf2f((unsigned short)st_l[row + (p >> 24)]);
            __builtin_nontemporal_store(r, &ov[idx]);
        }
        __syncthreads();
    }
}

// ---------------- fallback (no-ws fused kernel, f32 table) -----------------
__global__ __launch_bounds__(128)
void fused_kernel(const int* __restrict__ x, const int* __restrict__ add_table,
                  const float* __restrict__ st, float* __restrict__ out) {
    __shared__ unsigned px_lds[128 * 32];
    __shared__ int s_lds[128];
    const int t = threadIdx.x;
    const size_t chain0 = (size_t)blockIdx.x * 128;
    const vi4* xv = reinterpret_cast<const vi4*>(x + chain0 * O_DIM);
#pragma unroll 4
    for (int k = 0; k < 32; ++k) {
        const int idx = k * 128 + t;
        vi4 v = __builtin_nontemporal_load(&xv[idx]);
        unsigned p = (unsigned)v.x | ((unsigned)v.y << 8) |
                     ((unsigned)v.z << 16) | ((unsigned)v.w << 24);
        px_lds[(idx >> 5) * 32 + ((idx & 31) ^ ((idx >> 5) & 31))] = p;
    }
    __syncthreads();
    unsigned px[32];
#pragma unroll
    for (int k = 0; k < 32; ++k) px[k] = px_lds[t * 32 + (k ^ (t & 31))];
    int s = 0;
#pragma unroll
    for (int j = 0; j < O_DIM; ++j) {
        unsigned xj = (px[j >> 2] >> ((j & 3) * 8)) & 0xffu;
        s = add_table[((unsigned)j << 16) | ((unsigned)s << 8) | xj];
    }
    s_lds[t] = s;
    __syncthreads();
    vf4* ov = reinterpret_cast<vf4*>(out + chain0 * O_DIM);
#pragma unroll 4
    for (int k = 0; k < 32; ++k) {
        const int idx = k * 128 + t;
        const int chain = idx >> 5, q = idx & 31;
        unsigned p = px_lds[chain * 32 + (q ^ (chain & 31))];
        const float* row = st + ((unsigned)s_lds[chain] << 8);
        vf4 r;
        r.x = row[p & 0xffu]; r.y = row[(p >> 8) & 0xffu];
        r.z = row[(p >> 16) & 0xffu]; r.w = row[p >> 24];
        __builtin_nontemporal_store(r, &ov[idx]);
    }
}

extern "C" void kernel_launch(void* const* d_in, const int* in_sizes, int n_in,
                              void* d_out, int out_size, void* d_ws, size_t ws_size,
                              hipStream_t stream) {
    const int* x         = (const int*)d_in[0];
    const int* add_table = (const int*)d_in[1];
    const float* st      = (const float*)d_in[2];
    float* out           = (float*)d_out;

    if (ws_size >= (size_t)TAB_ENTRIES) {
        unsigned char* t8 = (unsigned char*)d_ws;
        pack_kernel<<<TAB_ENTRIES / 4 / 256, 256, 0, stream>>>(add_table, t8);
        fused_ws<<<(int)(NCHAINS / WCH), WBLK, 0, stream>>>(x, t8, st, out);
    } else {
        fused_kernel<<<(int)(NCHAINS / 128), 128, 0, stream>>>(x, add_table, st, out);
    }
}

// Round 10
// 184.866 us; speedup vs baseline: 1.0984x; 1.0984x over previous
//
#include <hip/hip_runtime.h>

// WhiteSoftmax: B=8192, C=64, O=128, 256 states, 256 vals.
//   K_pack:  add_table int32 -> u8 (8 MB ws) + softmax_table f32 -> bf16 (128 KB ws).
//   K_fused: 1024 thr x 2 chains = 2048 chains/block, 256 blocks (1/CU).
//     phase 1: coalesced x -> byte-pack -> LDS transpose -> px0/px1 regs.
//     phase 2: 128-step walk; 64 KB u8 table slice double-buffered in LDS via
//              global_load_lds(16B) + counted vmcnt(4) + raw s_barrier;
//              state gathers are ds_read_u8 (LDS) not global.
//     phase 3: stage st-bf16 from ws into dead slice LDS via global_load_lds
//              (no f32 read, no cvt); 16 chunks x 128 chains: owners deposit
//              px+s (linear layout -> ds_write_b128), all waves gather from
//              LDS + coalesced nontemporal float4 stores.

constexpr int O_DIM = 128;
constexpr long long NCHAINS = 8192LL * 64;        // 524288
constexpr int TAB_ENTRIES = 128 * 256 * 256;      // 8 MB u8
constexpr size_t ST16_OFF = 8u << 20;             // st bf16 at ws+8MB (128 KB)

typedef int   vi4 __attribute__((ext_vector_type(4)));
typedef float vf4 __attribute__((ext_vector_type(4)));

__device__ __forceinline__ unsigned f2bf(float f) {
    unsigned b = __float_as_uint(f);
    return (b + 0x7fffu + ((b >> 16) & 1u)) >> 16;
}
__device__ __forceinline__ float bf2f(unsigned short h) {
    return __uint_as_float(((unsigned)h) << 16);
}

// blocks [0,8192): table int32->u8. blocks [8192,8256): st f32->bf16.
__global__ __launch_bounds__(256)
void pack_kernel(const int* __restrict__ t32, unsigned char* __restrict__ t8,
                 const float* __restrict__ st, unsigned short* __restrict__ st16) {
    const int b = blockIdx.x;
    if (b < 8192) {
        const int i = (b * 256 + threadIdx.x) * 4;
        vi4 v = *reinterpret_cast<const vi4*>(t32 + i);
        unsigned w = ((unsigned)v.x & 0xffu) | (((unsigned)v.y & 0xffu) << 8) |
                     (((unsigned)v.z & 0xffu) << 16) | (((unsigned)v.w & 0xffu) << 24);
        *reinterpret_cast<unsigned*>(t8 + i) = w;
    } else if (st16) {
        const int i = (b - 8192) * 256 + threadIdx.x;   // 16384 vf4
        vf4 v = reinterpret_cast<const vf4*>(st)[i];
        unsigned* o = reinterpret_cast<unsigned*>(st16);
        o[i * 2]     = f2bf(v.x) | (f2bf(v.y) << 16);
        o[i * 2 + 1] = f2bf(v.z) | (f2bf(v.w) << 16);
    }
}

constexpr int WBLK = 1024;                        // threads per block
constexpr int WCH  = 2048;                        // chains per block (2/thread)

template <int ST16>
__global__ __launch_bounds__(WBLK, 4)
void fused_ws(const int* __restrict__ x, const unsigned char* __restrict__ t8,
              const float* __restrict__ st, const unsigned short* __restrict__ st16,
              float* __restrict__ out) {
    __shared__ unsigned char slice[2][65536];     // walk slices / p1 scratch / st bf16
    __shared__ unsigned px_out[128 * 32];         // 16 KB output px scratch (linear)
    __shared__ int s_l[128];
    unsigned* pxw = reinterpret_cast<unsigned*>(&slice[0][0]);

    const int t = threadIdx.x;
    const size_t chain0 = (size_t)blockIdx.x * WCH;

    unsigned px0[32], px1[32];

    // ---- phase 1: two 1024-chain windows: coalesced x load -> pack ->
    //      swizzled LDS transpose -> own-chain regs ----
    auto window = [&](int h, unsigned (&dst)[32]) {
        const vi4* xv = reinterpret_cast<const vi4*>(x + (chain0 + (size_t)h * 1024) * O_DIM);
#pragma unroll 4
        for (int k = 0; k < 32; ++k) {
            const int idx = k * WBLK + t;          // 32768 int4 in window tile
            vi4 v = __builtin_nontemporal_load(&xv[idx]);
            unsigned p = (unsigned)v.x | ((unsigned)v.y << 8) |
                         ((unsigned)v.z << 16) | ((unsigned)v.w << 24);
            const int cl = idx >> 5;               // 32 dwords per chain
            const int d  = idx & 31;
            pxw[cl * 32 + (d ^ (cl & 31))] = p;
        }
        __syncthreads();
#pragma unroll
        for (int k = 0; k < 32; ++k)
            dst[k] = pxw[t * 32 + (k ^ (t & 31))];
        __syncthreads();                           // pxw reads done before reuse
    };
    window(0, px0);
    window(1, px1);

    // ---- phase 2: 128-step walk, LDS slice double-buffer ----
    auto stage = [&](int j, int b) {
        const unsigned char* gsrc = t8 + ((size_t)j << 16);
#pragma unroll
        for (int r = 0; r < 4; ++r) {
            __builtin_amdgcn_global_load_lds(
                (const __attribute__((address_space(1))) void*)(gsrc + r * 16384 + t * 16),
                (__attribute__((address_space(3))) void*)(&slice[b][r * 16384 + t * 16]),
                16, 0, 0);
        }
    };

    stage(0, 0);
    asm volatile("s_waitcnt vmcnt(0)" ::: "memory");
    __builtin_amdgcn_s_barrier();

    int s0 = 0, s1 = 0;
#pragma unroll
    for (int j = 0; j < 127; ++j) {
        stage(j + 1, (j + 1) & 1);                     // issue next slice
        asm volatile("s_waitcnt vmcnt(4)" ::: "memory"); // slice j landed (my share)
        __builtin_amdgcn_s_barrier();                   // all waves' shares landed
        const int buf = j & 1;
        const unsigned xb0 = (px0[j >> 2] >> ((j & 3) * 8)) & 0xffu;
        const unsigned xb1 = (px1[j >> 2] >> ((j & 3) * 8)) & 0xffu;
        s0 = slice[buf][((unsigned)s0 << 8) | xb0];
        s1 = slice[buf][((unsigned)s1 << 8) | xb1];
        asm volatile("s_waitcnt lgkmcnt(0)" ::: "memory"); // my gathers done
        __builtin_amdgcn_s_barrier();                   // all gathers done before overwrite
    }
    asm volatile("s_waitcnt vmcnt(0)" ::: "memory");
    __builtin_amdgcn_s_barrier();
    {
        s0 = slice[1][((unsigned)s0 << 8) | (px0[31] >> 24)];
        s1 = slice[1][((unsigned)s1 << 8) | (px1[31] >> 24)];
    }
    __syncthreads();                                    // final gathers done, slices dead

    // ---- phase 3: st bf16 into slice LDS, chunked coalesced output ----
    unsigned short* st_l = reinterpret_cast<unsigned short*>(&slice[0][0]);
    if (ST16) {
        // stage precomputed bf16 table straight into LDS (128 KB, linear)
        const unsigned char* ssrc = reinterpret_cast<const unsigned char*>(st16);
        unsigned char* sdst = &slice[0][0];
#pragma unroll
        for (int r = 0; r < 8; ++r) {
            __builtin_amdgcn_global_load_lds(
                (const __attribute__((address_space(1))) void*)(ssrc + r * 16384 + t * 16),
                (__attribute__((address_space(3))) void*)(sdst + r * 16384 + t * 16),
                16, 0, 0);
        }
        asm volatile("s_waitcnt vmcnt(0)" ::: "memory");
    } else {
        unsigned* stl32 = reinterpret_cast<unsigned*>(&slice[0][0]);
        const vf4* stv = reinterpret_cast<const vf4*>(st);
#pragma unroll 4
        for (int k = 0; k < 16; ++k) {
            const int idx = k * WBLK + t;          // 16384 vf4 = 64K floats
            vf4 v = stv[idx];
            stl32[idx * 2]     = f2bf(v.x) | (f2bf(v.y) << 16);
            stl32[idx * 2 + 1] = f2bf(v.z) | (f2bf(v.w) << 16);
        }
    }
    __syncthreads();

    auto do_chunks = [&](const unsigned (&pp)[32], int sreg, int w) {
        for (int c = 0; c < 8; ++c) {
            if ((t >> 7) == c) {                   // owner threads deposit px + s
                const int lc = t & 127;
                s_l[lc] = sreg;
#pragma unroll
                for (int k = 0; k < 32; ++k)
                    px_out[lc * 32 + k] = pp[k];   // linear -> ds_write_b128
            }
            __syncthreads();
            vf4* ov = reinterpret_cast<vf4*>(
                out + (chain0 + (size_t)w * 1024 + (size_t)c * 128) * O_DIM);
#pragma unroll
            for (int k = 0; k < 4; ++k) {
                const int idx = k * WBLK + t;      // 4096 vf4 per chunk
                const int cl = idx >> 5, q = idx & 31;
                unsigned p = px_out[cl * 32 + q];  // linear, conflict-free
                const int row = s_l[cl] << 8;
                vf4 r;
                r.x = bf2f((unsigned short)st_l[row + (p & 0xffu)]);
                r.y = bf2f((unsigned short)st_l[row + ((p >> 8) & 0xffu)]);
                r.z = bf2f((unsigned short)st_l[row + ((p >> 16) & 0xffu)]);
                r.w = bf2f((unsigned short)st_l[row + (p >> 24)]);
                __builtin_nontemporal_store(r, &ov[idx]);
            }
            __syncthreads();
        }
    };
    do_chunks(px0, s0, 0);
    do_chunks(px1, s1, 1);
}

// ---------------- fallback (no-ws fused kernel, f32 table) -----------------
__global__ __launch_bounds__(128)
void fused_kernel(const int* __restrict__ x, const int* __restrict__ add_table,
                  const float* __restrict__ st, float* __restrict__ out) {
    __shared__ unsigned px_lds[128 * 32];
    __shared__ int s_lds[128];
    const int t = threadIdx.x;
    const size_t chain0 = (size_t)blockIdx.x * 128;
    const vi4* xv = reinterpret_cast<const vi4*>(x + chain0 * O_DIM);
#pragma unroll 4
    for (int k = 0; k < 32; ++k) {
        const int idx = k * 128 + t;
        vi4 v = __builtin_nontemporal_load(&xv[idx]);
        unsigned p = (unsigned)v.x | ((unsigned)v.y << 8) |
                     ((unsigned)v.z << 16) | ((unsigned)v.w << 24);
        px_lds[(idx >> 5) * 32 + ((idx & 31) ^ ((idx >> 5) & 31))] = p;
    }
    __syncthreads();
    unsigned px[32];
#pragma unroll
    for (int k = 0; k < 32; ++k) px[k] = px_lds[t * 32 + (k ^ (t & 31))];
    int s = 0;
#pragma unroll
    for (int j = 0; j < O_DIM; ++j) {
        unsigned xj = (px[j >> 2] >> ((j & 3) * 8)) & 0xffu;
        s = add_table[((unsigned)j << 16) | ((unsigned)s << 8) | xj];
    }
    s_lds[t] = s;
    __syncthreads();
    vf4* ov = reinterpret_cast<vf4*>(out + chain0 * O_DIM);
#pragma unroll 4
    for (int k = 0; k < 32; ++k) {
        const int idx = k * 128 + t;
        const int chain = idx >> 5, q = idx & 31;
        unsigned p = px_lds[chain * 32 + (q ^ (chain & 31))];
        const float* row = st + ((unsigned)s_lds[chain] << 8);
        vf4 r;
        r.x = row[p & 0xffu]; r.y = row[(p >> 8) & 0xffu];
        r.z = row[(p >> 16) & 0xffu]; r.w = row[p >> 24];
        __builtin_nontemporal_store(r, &ov[idx]);
    }
}

extern "C" void kernel_launch(void* const* d_in, const int* in_sizes, int n_in,
                              void* d_out, int out_size, void* d_ws, size_t ws_size,
                              hipStream_t stream) {
    const int* x         = (const int*)d_in[0];
    const int* add_table = (const int*)d_in[1];
    const float* st      = (const float*)d_in[2];
    float* out           = (float*)d_out;
    char* ws             = (char*)d_ws;

    if (ws_size >= ST16_OFF + 131072) {
        unsigned char* t8     = (unsigned char*)ws;
        unsigned short* st16  = (unsigned short*)(ws + ST16_OFF);
        pack_kernel<<<8256, 256, 0, stream>>>(add_table, t8, st, st16);
        fused_ws<1><<<(int)(NCHAINS / WCH), WBLK, 0, stream>>>(x, t8, st, st16, out);
    } else if (ws_size >= (size_t)TAB_ENTRIES) {
        unsigned char* t8 = (unsigned char*)ws;
        pack_kernel<<<8192, 256, 0, stream>>>(add_table, t8, st, nullptr);
        fused_ws<0><<<(int)(NCHAINS / WCH), WBLK, 0, stream>>>(x, t8, st, nullptr, out);
    } else {
        fused_kernel<<<(int)(NCHAINS / 128), 128, 0, stream>>>(x, add_table, st, out);
    }
}

// Round 12
// 183.520 us; speedup vs baseline: 1.1065x; 1.0073x over previous
//
#include <hip/hip_runtime.h>

// WhiteSoftmax: B=8192, C=64, O=128, 256 states, 256 vals.
//   K_pack:  add_table int32 -> u8 (8 MB ws) + softmax_table f32 -> bf16 (128 KB ws).
//   K_fused: 1024 thr x 2 chains = 2048 chains/block, 256 blocks (1/CU).
//     phase 1: coalesced x -> byte-pack -> LDS transpose -> px0/px1 regs.
//     phase 2: 128-step walk; 64 KB u8 table slice double-buffered in LDS via
//              global_load_lds(16B) + counted vmcnt(4) + raw s_barrier;
//              state gathers are ds_read_u8 (LDS) not global.
//     phase 3: st16 (bf16) staged into dead slice LDS (128 KB spans BOTH
//              slices -- must happen after the final gather, round-11 lesson);
//              16 chunks x 128 chains: owners deposit px+s with XOR swizzle
//              (linear deposit = 32-way WRITE conflict, round-10 lesson);
//              all waves gather bf16 from LDS + coalesced nontemporal stores.

constexpr int O_DIM = 128;
constexpr long long NCHAINS = 8192LL * 64;        // 524288
constexpr int TAB_ENTRIES = 128 * 256 * 256;      // 8 MB u8
constexpr size_t ST16_OFF = 8u << 20;             // st bf16 at ws+8MB (128 KB)

typedef int   vi4 __attribute__((ext_vector_type(4)));
typedef float vf4 __attribute__((ext_vector_type(4)));

__device__ __forceinline__ unsigned f2bf(float f) {
    unsigned b = __float_as_uint(f);
    return (b + 0x7fffu + ((b >> 16) & 1u)) >> 16;
}
__device__ __forceinline__ float bf2f(unsigned short h) {
    return __uint_as_float(((unsigned)h) << 16);
}

// blocks [0,8192): table int32->u8. blocks [8192,8256): st f32->bf16.
__global__ __launch_bounds__(256)
void pack_kernel(const int* __restrict__ t32, unsigned char* __restrict__ t8,
                 const float* __restrict__ st, unsigned short* __restrict__ st16) {
    const int b = blockIdx.x;
    if (b < 8192) {
        const int i = (b * 256 + threadIdx.x) * 4;
        vi4 v = *reinterpret_cast<const vi4*>(t32 + i);
        unsigned w = ((unsigned)v.x & 0xffu) | (((unsigned)v.y & 0xffu) << 8) |
                     (((unsigned)v.z & 0xffu) << 16) | (((unsigned)v.w & 0xffu) << 24);
        *reinterpret_cast<unsigned*>(t8 + i) = w;
    } else if (st16) {
        const int i = (b - 8192) * 256 + threadIdx.x;   // 16384 vf4
        vf4 v = reinterpret_cast<const vf4*>(st)[i];
        unsigned* o = reinterpret_cast<unsigned*>(st16);
        o[i * 2]     = f2bf(v.x) | (f2bf(v.y) << 16);
        o[i * 2 + 1] = f2bf(v.z) | (f2bf(v.w) << 16);
    }
}

constexpr int WBLK = 1024;                        // threads per block
constexpr int WCH  = 2048;                        // chains per block (2/thread)

template <int ST16>
__global__ __launch_bounds__(WBLK, 4)
void fused_ws(const int* __restrict__ x, const unsigned char* __restrict__ t8,
              const float* __restrict__ st, const unsigned short* __restrict__ st16,
              float* __restrict__ out) {
    __shared__ unsigned char slice[2][65536];     // walk slices / p1 scratch / st bf16
    __shared__ unsigned px_out[128 * 32];         // 16 KB output px scratch (swizzled)
    __shared__ int s_l[128];
    unsigned* pxw = reinterpret_cast<unsigned*>(&slice[0][0]);

    const int t = threadIdx.x;
    const size_t chain0 = (size_t)blockIdx.x * WCH;

    unsigned px0[32], px1[32];

    // ---- phase 1: two 1024-chain windows: coalesced x load -> pack ->
    //      swizzled LDS transpose -> own-chain regs ----
    auto window = [&](int h, unsigned (&dst)[32]) {
        const vi4* xv = reinterpret_cast<const vi4*>(x + (chain0 + (size_t)h * 1024) * O_DIM);
#pragma unroll 4
        for (int k = 0; k < 32; ++k) {
            const int idx = k * WBLK + t;          // 32768 int4 in window tile
            vi4 v = __builtin_nontemporal_load(&xv[idx]);
            unsigned p = (unsigned)v.x | ((unsigned)v.y << 8) |
                         ((unsigned)v.z << 16) | ((unsigned)v.w << 24);
            const int cl = idx >> 5;               // 32 dwords per chain
            const int d  = idx & 31;
            pxw[cl * 32 + (d ^ (cl & 31))] = p;
        }
        __syncthreads();
#pragma unroll
        for (int k = 0; k < 32; ++k)
            dst[k] = pxw[t * 32 + (k ^ (t & 31))];
        __syncthreads();                           // pxw reads done before reuse
    };
    window(0, px0);
    window(1, px1);

    // ---- phase 2: 128-step walk, LDS slice double-buffer ----
    auto stage = [&](int j, int b) {
        const unsigned char* gsrc = t8 + ((size_t)j << 16);
#pragma unroll
        for (int r = 0; r < 4; ++r) {
            __builtin_amdgcn_global_load_lds(
                (const __attribute__((address_space(1))) void*)(gsrc + r * 16384 + t * 16),
                (__attribute__((address_space(3))) void*)(&slice[b][r * 16384 + t * 16]),
                16, 0, 0);
        }
    };

    stage(0, 0);
    asm volatile("s_waitcnt vmcnt(0)" ::: "memory");
    __builtin_amdgcn_s_barrier();

    int s0 = 0, s1 = 0;
#pragma unroll
    for (int j = 0; j < 127; ++j) {
        stage(j + 1, (j + 1) & 1);                     // issue next slice
        asm volatile("s_waitcnt vmcnt(4)" ::: "memory"); // slice j landed (my share)
        __builtin_amdgcn_s_barrier();                   // all waves' shares landed
        const int buf = j & 1;
        const unsigned xb0 = (px0[j >> 2] >> ((j & 3) * 8)) & 0xffu;
        const unsigned xb1 = (px1[j >> 2] >> ((j & 3) * 8)) & 0xffu;
        s0 = slice[buf][((unsigned)s0 << 8) | xb0];
        s1 = slice[buf][((unsigned)s1 << 8) | xb1];
        asm volatile("s_waitcnt lgkmcnt(0)" ::: "memory"); // my gathers done
        __builtin_amdgcn_s_barrier();                   // all gathers done before overwrite
    }
    asm volatile("s_waitcnt vmcnt(0)" ::: "memory");
    __builtin_amdgcn_s_barrier();
    {
        s0 = slice[1][((unsigned)s0 << 8) | (px0[31] >> 24)];
        s1 = slice[1][((unsigned)s1 << 8) | (px1[31] >> 24)];
    }
    __syncthreads();                                    // all final gathers done, slices dead

    // ---- phase 3: st bf16 into slice LDS (128 KB, spans both slices) ----
    unsigned short* st_l = reinterpret_cast<unsigned short*>(&slice[0][0]);
    if (ST16) {
        const unsigned char* ssrc = reinterpret_cast<const unsigned char*>(st16);
        unsigned char* sdst = &slice[0][0];
#pragma unroll
        for (int r = 0; r < 8; ++r) {
            __builtin_amdgcn_global_load_lds(
                (const __attribute__((address_space(1))) void*)(ssrc + r * 16384 + t * 16),
                (__attribute__((address_space(3))) void*)(sdst + r * 16384 + t * 16),
                16, 0, 0);
        }
        asm volatile("s_waitcnt vmcnt(0)" ::: "memory");
    } else {
        unsigned* stl32 = reinterpret_cast<unsigned*>(&slice[0][0]);
        const vf4* stv = reinterpret_cast<const vf4*>(st);
#pragma unroll 4
        for (int k = 0; k < 16; ++k) {
            const int idx = k * WBLK + t;          // 16384 vf4 = 64K floats
            vf4 v = stv[idx];
            stl32[idx * 2]     = f2bf(v.x) | (f2bf(v.y) << 16);
            stl32[idx * 2 + 1] = f2bf(v.z) | (f2bf(v.w) << 16);
        }
    }
    __syncthreads();

    // ---- chunked coalesced output ----
    auto do_chunks = [&](const unsigned (&pp)[32], int sreg, int w) {
        for (int c = 0; c < 8; ++c) {
            if ((t >> 7) == c) {                   // owner threads deposit px + s
                const int lc = t & 127;
                s_l[lc] = sreg;
#pragma unroll
                for (int k = 0; k < 32; ++k)
                    px_out[lc * 32 + (k ^ (lc & 31))] = pp[k];  // XOR: conflict-free writes
            }
            __syncthreads();
            vf4* ov = reinterpret_cast<vf4*>(
                out + (chain0 + (size_t)w * 1024 + (size_t)c * 128) * O_DIM);
#pragma unroll
            for (int k = 0; k < 4; ++k) {
                const int idx = k * WBLK + t;      // 4096 vf4 per chunk
                const int cl = idx >> 5, q = idx & 31;
                unsigned p = px_out[cl * 32 + (q ^ (cl & 31))];
                const int row = s_l[cl] << 8;
                vf4 r;
                r.x = bf2f((unsigned short)st_l[row + (p & 0xffu)]);
                r.y = bf2f((unsigned short)st_l[row + ((p >> 8) & 0xffu)]);
                r.z = bf2f((unsigned short)st_l[row + ((p >> 16) & 0xffu)]);
                r.w = bf2f((unsigned short)st_l[row + (p >> 24)]);
                __builtin_nontemporal_store(r, &ov[idx]);
            }
            __syncthreads();
        }
    };
    do_chunks(px0, s0, 0);
    do_chunks(px1, s1, 1);
}

// ---------------- fallback (no-ws fused kernel, f32 table) -----------------
__global__ __launch_bounds__(128)
void fused_kernel(const int* __restrict__ x, const int* __restrict__ add_table,
                  const float* __restrict__ st, float* __restrict__ out) {
    __shared__ unsigned px_lds[128 * 32];
    __shared__ int s_lds[128];
    const int t = threadIdx.x;
    const size_t chain0 = (size_t)blockIdx.x * 128;
    const vi4* xv = reinterpret_cast<const vi4*>(x + chain0 * O_DIM);
#pragma unroll 4
    for (int k = 0; k < 32; ++k) {
        const int idx = k * 128 + t;
        vi4 v = __builtin_nontemporal_load(&xv[idx]);
        unsigned p = (unsigned)v.x | ((unsigned)v.y << 8) |
                     ((unsigned)v.z << 16) | ((unsigned)v.w << 24);
        px_lds[(idx >> 5) * 32 + ((idx & 31) ^ ((idx >> 5) & 31))] = p;
    }
    __syncthreads();
    unsigned px[32];
#pragma unroll
    for (int k = 0; k < 32; ++k) px[k] = px_lds[t * 32 + (k ^ (t & 31))];
    int s = 0;
#pragma unroll
    for (int j = 0; j < O_DIM; ++j) {
        unsigned xj = (px[j >> 2] >> ((j & 3) * 8)) & 0xffu;
        s = add_table[((unsigned)j << 16) | ((unsigned)s << 8) | xj];
    }
    s_lds[t] = s;
    __syncthreads();
    vf4* ov = reinterpret_cast<vf4*>(out + chain0 * O_DIM);
#pragma unroll 4
    for (int k = 0; k < 32; ++k) {
        const int idx = k * 128 + t;
        const int chain = idx >> 5, q = idx & 31;
        unsigned p = px_lds[chain * 32 + (q ^ (chain & 31))];
        const float* row = st + ((unsigned)s_lds[chain] << 8);
        vf4 r;
        r.x = row[p & 0xffu]; r.y = row[(p >> 8) & 0xffu];
        r.z = row[(p >> 16) & 0xffu]; r.w = row[p >> 24];
        __builtin_nontemporal_store(r, &ov[idx]);
    }
}

extern "C" void kernel_launch(void* const* d_in, const int* in_sizes, int n_in,
                              void* d_out, int out_size, void* d_ws, size_t ws_size,
                              hipStream_t stream) {
    const int* x         = (const int*)d_in[0];
    const int* add_table = (const int*)d_in[1];
    const float* st      = (const float*)d_in[2];
    float* out           = (float*)d_out;
    char* ws             = (char*)d_ws;

    if (ws_size >= ST16_OFF + 131072) {
        unsigned char* t8     = (unsigned char*)ws;
        unsigned short* st16  = (unsigned short*)(ws + ST16_OFF);
        pack_kernel<<<8256, 256, 0, stream>>>(add_table, t8, st, st16);
        fused_ws<1><<<(int)(NCHAINS / WCH), WBLK, 0, stream>>>(x, t8, st, st16, out);
    } else if (ws_size >= (size_t)TAB_ENTRIES) {
        unsigned char* t8 = (unsigned char*)ws;
        pack_kernel<<<8192, 256, 0, stream>>>(add_table, t8, st, nullptr);
        fused_ws<0><<<(int)(NCHAINS / WCH), WBLK, 0, stream>>>(x, t8, st, nullptr, out);
    } else {
        fused_kernel<<<(int)(NCHAINS / 128), 128, 0, stream>>>(x, add_table, st, out);
    }
}

// Round 13
// 168.785 us; speedup vs baseline: 1.2030x; 1.0873x over previous
//
#include <hip/hip_runtime.h>

// WhiteSoftmax: B=8192, C=64, O=128, 256 states, 256 vals.
//   K_pack:  add_table int32 -> u8 (8 MB ws) + softmax_table f32 -> bf16 (128 KB ws).
//   K_fused: 1024 thr x 2 chains = 2048 chains/block, 256 blocks (1/CU).
//     phase 1: coalesced x -> byte-pack -> LDS transpose -> px0/px1 regs.
//     phase 2: 128-step walk. Reg-staged 2-deep pipeline (T14): slice j in LDS
//              being gathered, slice j+1 in VGPRs (4x int4/thread), slice j+2
//              in flight from L2. Per step: gathers -> vmcnt(0) -> ds_write
//              slice j+1 -> prefetch j+2 -> lgkmcnt(0) -> ONE s_barrier.
//              (ds_write is wave-issued, so lgkm+barrier seals it -- unlike
//              the DMA global_load_lds path which needed 2 barriers/step.)
//     phase 3: st16 (bf16) staged into dead slice LDS (after final gather --
//              round-11 lesson: 128 KB spans BOTH slices); 16 chunks x 128
//              chains, owners deposit px+s with XOR swizzle (linear deposit =
//              32-way WRITE conflict, round-10 lesson); coalesced nt stores.

constexpr int O_DIM = 128;
constexpr long long NCHAINS = 8192LL * 64;        // 524288
constexpr int TAB_ENTRIES = 128 * 256 * 256;      // 8 MB u8
constexpr size_t ST16_OFF = 8u << 20;             // st bf16 at ws+8MB (128 KB)

typedef int   vi4 __attribute__((ext_vector_type(4)));
typedef float vf4 __attribute__((ext_vector_type(4)));

__device__ __forceinline__ unsigned f2bf(float f) {
    unsigned b = __float_as_uint(f);
    return (b + 0x7fffu + ((b >> 16) & 1u)) >> 16;
}
__device__ __forceinline__ float bf2f(unsigned short h) {
    return __uint_as_float(((unsigned)h) << 16);
}

// blocks [0,8192): table int32->u8. blocks [8192,8256): st f32->bf16.
__global__ __launch_bounds__(256)
void pack_kernel(const int* __restrict__ t32, unsigned char* __restrict__ t8,
                 const float* __restrict__ st, unsigned short* __restrict__ st16) {
    const int b = blockIdx.x;
    if (b < 8192) {
        const int i = (b * 256 + threadIdx.x) * 4;
        vi4 v = *reinterpret_cast<const vi4*>(t32 + i);
        unsigned w = ((unsigned)v.x & 0xffu) | (((unsigned)v.y & 0xffu) << 8) |
                     (((unsigned)v.z & 0xffu) << 16) | (((unsigned)v.w & 0xffu) << 24);
        *reinterpret_cast<unsigned*>(t8 + i) = w;
    } else if (st16) {
        const int i = (b - 8192) * 256 + threadIdx.x;   // 16384 vf4
        vf4 v = reinterpret_cast<const vf4*>(st)[i];
        unsigned* o = reinterpret_cast<unsigned*>(st16);
        o[i * 2]     = f2bf(v.x) | (f2bf(v.y) << 16);
        o[i * 2 + 1] = f2bf(v.z) | (f2bf(v.w) << 16);
    }
}

constexpr int WBLK = 1024;                        // threads per block
constexpr int WCH  = 2048;                        // chains per block (2/thread)

template <int ST16>
__global__ __launch_bounds__(WBLK, 4)
void fused_ws(const int* __restrict__ x, const unsigned char* __restrict__ t8,
              const float* __restrict__ st, const unsigned short* __restrict__ st16,
              float* __restrict__ out) {
    __shared__ unsigned char slice[2][65536];     // walk slices / p1 scratch / st bf16
    __shared__ unsigned px_out[128 * 32];         // 16 KB output px scratch (swizzled)
    __shared__ int s_l[128];
    unsigned* pxw = reinterpret_cast<unsigned*>(&slice[0][0]);

    const int t = threadIdx.x;
    const size_t chain0 = (size_t)blockIdx.x * WCH;

    unsigned px0[32], px1[32];

    // ---- phase 1: two 1024-chain windows: coalesced x load -> pack ->
    //      swizzled LDS transpose -> own-chain regs ----
    auto window = [&](int h, unsigned (&dst)[32]) {
        const vi4* xv = reinterpret_cast<const vi4*>(x + (chain0 + (size_t)h * 1024) * O_DIM);
#pragma unroll 4
        for (int k = 0; k < 32; ++k) {
            const int idx = k * WBLK + t;          // 32768 int4 in window tile
            vi4 v = __builtin_nontemporal_load(&xv[idx]);
            unsigned p = (unsigned)v.x | ((unsigned)v.y << 8) |
                         ((unsigned)v.z << 16) | ((unsigned)v.w << 24);
            const int cl = idx >> 5;               // 32 dwords per chain
            const int d  = idx & 31;
            pxw[cl * 32 + (d ^ (cl & 31))] = p;
        }
        __syncthreads();
#pragma unroll
        for (int k = 0; k < 32; ++k)
            dst[k] = pxw[t * 32 + (k ^ (t & 31))];
        __syncthreads();                           // pxw reads done before reuse
    };
    window(0, px0);
    window(1, px1);

    // ---- phase 2: 128-step walk, reg-staged 2-deep pipeline ----
    // Prologue: DMA slice 0 -> buf0; prefetch slice 1 -> regs.
    {
        const unsigned char* gsrc = t8;            // slice 0
#pragma unroll
        for (int r = 0; r < 4; ++r) {
            __builtin_amdgcn_global_load_lds(
                (const __attribute__((address_space(1))) void*)(gsrc + r * 16384 + t * 16),
                (__attribute__((address_space(3))) void*)(&slice[0][r * 16384 + t * 16]),
                16, 0, 0);
        }
    }
    vi4 pf0, pf1, pf2, pf3;
    {
        const vi4* g = reinterpret_cast<const vi4*>(t8 + (1ull << 16));
        pf0 = g[t]; pf1 = g[1024 + t]; pf2 = g[2048 + t]; pf3 = g[3072 + t];
    }
    asm volatile("s_waitcnt vmcnt(4)" ::: "memory");   // slice-0 DMA (oldest 4) landed
    __builtin_amdgcn_s_barrier();

    int s0 = 0, s1 = 0;
#pragma unroll
    for (int j = 0; j < 127; ++j) {
        const int buf = j & 1;
        // issue this step's gathers (latency hidden under writes/prefetch below)
        const unsigned xb0 = (px0[j >> 2] >> ((j & 3) * 8)) & 0xffu;
        const unsigned xb1 = (px1[j >> 2] >> ((j & 3) * 8)) & 0xffu;
        s0 = slice[buf][((unsigned)s0 << 8) | xb0];
        s1 = slice[buf][((unsigned)s1 << 8) | xb1];
        // slice j+1 regs landed (issued a full iteration ago)
        asm volatile("s_waitcnt vmcnt(0)" ::: "memory");
        // write slice j+1 into the other buffer (gathered-from in iter j-1,
        // sealed by that iter's lgkmcnt+barrier -> safe with ONE barrier/step)
        {
            vi4* dst = reinterpret_cast<vi4*>(&slice[buf ^ 1][0]);
            dst[t] = pf0; dst[1024 + t] = pf1; dst[2048 + t] = pf2; dst[3072 + t] = pf3;
        }
        // prefetch slice j+2
        if (j <= 125) {
            const vi4* g = reinterpret_cast<const vi4*>(t8 + ((size_t)(j + 2) << 16));
            pf0 = g[t]; pf1 = g[1024 + t]; pf2 = g[2048 + t]; pf3 = g[3072 + t];
        }
        asm volatile("s_waitcnt lgkmcnt(0)" ::: "memory"); // own gathers + ds_writes done
        __builtin_amdgcn_s_barrier();                      // all waves' writes/gathers done
    }
    // j = 127: final gather from buf[1]
    {
        s0 = slice[1][((unsigned)s0 << 8) | (px0[31] >> 24)];
        s1 = slice[1][((unsigned)s1 << 8) | (px1[31] >> 24)];
    }
    __syncthreads();                                    // all final gathers done, slices dead

    // ---- phase 3: st bf16 into slice LDS (128 KB, spans both slices) ----
    unsigned short* st_l = reinterpret_cast<unsigned short*>(&slice[0][0]);
    if (ST16) {
        const unsigned char* ssrc = reinterpret_cast<const unsigned char*>(st16);
        unsigned char* sdst = &slice[0][0];
#pragma unroll
        for (int r = 0; r < 8; ++r) {
            __builtin_amdgcn_global_load_lds(
                (const __attribute__((address_space(1))) void*)(ssrc + r * 16384 + t * 16),
                (__attribute__((address_space(3))) void*)(sdst + r * 16384 + t * 16),
                16, 0, 0);
        }
        asm volatile("s_waitcnt vmcnt(0)" ::: "memory");
    } else {
        unsigned* stl32 = reinterpret_cast<unsigned*>(&slice[0][0]);
        const vf4* stv = reinterpret_cast<const vf4*>(st);
#pragma unroll 4
        for (int k = 0; k < 16; ++k) {
            const int idx = k * WBLK + t;          // 16384 vf4 = 64K floats
            vf4 v = stv[idx];
            stl32[idx * 2]     = f2bf(v.x) | (f2bf(v.y) << 16);
            stl32[idx * 2 + 1] = f2bf(v.z) | (f2bf(v.w) << 16);
        }
    }
    __syncthreads();

    // ---- chunked coalesced output ----
    auto do_chunks = [&](const unsigned (&pp)[32], int sreg, int w) {
        for (int c = 0; c < 8; ++c) {
            if ((t >> 7) == c) {                   // owner threads deposit px + s
                const int lc = t & 127;
                s_l[lc] = sreg;
#pragma unroll
                for (int k = 0; k < 32; ++k)
                    px_out[lc * 32 + (k ^ (lc & 31))] = pp[k];  // XOR: conflict-free writes
            }
            __syncthreads();
            vf4* ov = reinterpret_cast<vf4*>(
                out + (chain0 + (size_t)w * 1024 + (size_t)c * 128) * O_DIM);
#pragma unroll
            for (int k = 0; k < 4; ++k) {
                const int idx = k * WBLK + t;      // 4096 vf4 per chunk
                const int cl = idx >> 5, q = idx & 31;
                unsigned p = px_out[cl * 32 + (q ^ (cl & 31))];
                const int row = s_l[cl] << 8;
                vf4 r;
                r.x = bf2f((unsigned short)st_l[row + (p & 0xffu)]);
                r.y = bf2f((unsigned short)st_l[row + ((p >> 8) & 0xffu)]);
                r.z = bf2f((unsigned short)st_l[row + ((p >> 16) & 0xffu)]);
                r.w = bf2f((unsigned short)st_l[row + (p >> 24)]);
                __builtin_nontemporal_store(r, &ov[idx]);
            }
            __syncthreads();
        }
    };
    do_chunks(px0, s0, 0);
    do_chunks(px1, s1, 1);
}

// ---------------- fallback (no-ws fused kernel, f32 table) -----------------
__global__ __launch_bounds__(128)
void fused_kernel(const int* __restrict__ x, const int* __restrict__ add_table,
                  const float* __restrict__ st, float* __restrict__ out) {
    __shared__ unsigned px_lds[128 * 32];
    __shared__ int s_lds[128];
    const int t = threadIdx.x;
    const size_t chain0 = (size_t)blockIdx.x * 128;
    const vi4* xv = reinterpret_cast<const vi4*>(x + chain0 * O_DIM);
#pragma unroll 4
    for (int k = 0; k < 32; ++k) {
        const int idx = k * 128 + t;
        vi4 v = __builtin_nontemporal_load(&xv[idx]);
        unsigned p = (unsigned)v.x | ((unsigned)v.y << 8) |
                     ((unsigned)v.z << 16) | ((unsigned)v.w << 24);
        px_lds[(idx >> 5) * 32 + ((idx & 31) ^ ((idx >> 5) & 31))] = p;
    }
    __syncthreads();
    unsigned px[32];
#pragma unroll
    for (int k = 0; k < 32; ++k) px[k] = px_lds[t * 32 + (k ^ (t & 31))];
    int s = 0;
#pragma unroll
    for (int j = 0; j < O_DIM; ++j) {
        unsigned xj = (px[j >> 2] >> ((j & 3) * 8)) & 0xffu;
        s = add_table[((unsigned)j << 16) | ((unsigned)s << 8) | xj];
    }
    s_lds[t] = s;
    __syncthreads();
    vf4* ov = reinterpret_cast<vf4*>(out + chain0 * O_DIM);
#pragma unroll 4
    for (int k = 0; k < 32; ++k) {
        const int idx = k * 128 + t;
        const int chain = idx >> 5, q = idx & 31;
        unsigned p = px_lds[chain * 32 + (q ^ (chain & 31))];
        const float* row = st + ((unsigned)s_lds[chain] << 8);
        vf4 r;
        r.x = row[p & 0xffu]; r.y = row[(p >> 8) & 0xffu];
        r.z = row[(p >> 16) & 0xffu]; r.w = row[p >> 24];
        __builtin_nontemporal_store(r, &ov[idx]);
    }
}

extern "C" void kernel_launch(void* const* d_in, const int* in_sizes, int n_in,
                              void* d_out, int out_size, void* d_ws, size_t ws_size,
                              hipStream_t stream) {
    const int* x         = (const int*)d_in[0];
    const int* add_table = (const int*)d_in[1];
    const float* st      = (const float*)d_in[2];
    float* out           = (float*)d_out;
    char* ws             = (char*)d_ws;

    if (ws_size >= ST16_OFF + 131072) {
        unsigned char* t8     = (unsigned char*)ws;
        unsigned short* st16  = (unsigned short*)(ws + ST16_OFF);
        pack_kernel<<<8256, 256, 0, stream>>>(add_table, t8, st, st16);
        fused_ws<1><<<(int)(NCHAINS / WCH), WBLK, 0, stream>>>(x, t8, st, st16, out);
    } else if (ws_size >= (size_t)TAB_ENTRIES) {
        unsigned char* t8 = (unsigned char*)ws;
        pack_kernel<<<8192, 256, 0, stream>>>(add_table, t8, st, nullptr);
        fused_ws<0><<<(int)(NCHAINS / WCH), WBLK, 0, stream>>>(x, t8, st, nullptr, out);
    } else {
        fused_kernel<<<(int)(NCHAINS / 128), 128, 0, stream>>>(x, add_table, st, out);
    }
}